// Round 2
// baseline (505.272 us; speedup 1.0000x reference)
//
#include <hip/hip_runtime.h>
#include <math.h>

#define N_SLOTS 524288
#define DIM_MEM 128
#define DIM_IN 1024
#define NFACT 138
#define EPSF 1e-8f
#define ROWS_PB 64          // rows per block: 8 half-waves x 8 rows

// ws layout (bytes), first 4096 zeroed each call:
//   0    : float factors[138]   (atomic accumulation target)
//   1024 : float derived[16]    d0=key_s/key_norm, d1..d7=shift_w, d8=sharpening
//   2048 : double P_acc         (sum of t^sh)
//   2176 : float num[128]       (unnormalized read vector)

// ---- Stage 1: factors = x @ W + b  (1024 x 138) ----
__global__ __launch_bounds__(256) void k_factors(const float* __restrict__ x,
                                                 const float* __restrict__ W,
                                                 const float* __restrict__ b,
                                                 float* __restrict__ factors) {
    int j = threadIdx.x;            // factor column
    int i0 = blockIdx.x * 32;       // 32 input rows per block, 32 blocks
    if (j < NFACT) {
        float acc = 0.f;
        #pragma unroll 8
        for (int i = i0; i < i0 + 32; ++i)
            acc = fmaf(x[i], W[(size_t)i * NFACT + j], acc);   // consecutive j -> coalesced
        if (blockIdx.x == 0) acc += b[j];
        atomicAdd(&factors[j], acc);
    }
}

// ---- Stage 2: derived scalars ----
// gate = softmax over ONE element == 1.0 exactly -> previous_weighting is dead.
// The content-softmax denominator S cancels in (t/S)^sh / sum((t/S)^sh), so it
// is never computed.
__global__ void k_derived(const float* __restrict__ f, float* __restrict__ d) {
    int l = threadIdx.x;            // 64 threads
    float v = f[l] * f[l] + f[l + 64] * f[l + 64];
    for (int off = 32; off; off >>= 1) v += __shfl_xor(v, off, 64);
    if (l == 0) {
        float key_norm = fmaxf(sqrtf(v), EPSF);
        d[0] = f[128] / key_norm;                  // key_s / key_norm
        float m = f[130];
        for (int j = 1; j < 7; ++j) m = fmaxf(m, f[130 + j]);
        float e[7], s = 0.f;
        for (int j = 0; j < 7; ++j) { e[j] = expf(f[130 + j] - m); s += e[j]; }
        for (int j = 0; j < 7; ++j) d[1 + j] = e[j] / s;       // shift weights
        d[8] = fmaxf(f[137], 0.f) + 1.f;                       // sharpening
    }
}

// ---- Stage 3: fused single pass over memory ----
// Each block owns 64 contiguous rows (held in registers), computes
// e = exp(d0 * dot(row,key)/||row||) for rows + 3-row halo each side,
// applies the 7-tap circular stencil + sharpening from LDS, and accumulates
// num += t^sh * row and P += t^sh. Normalization deferred to k_final.
__global__ __launch_bounds__(256) void k_main(const float* __restrict__ mem,
                                              const float* __restrict__ keyv,
                                              const float* __restrict__ der,
                                              float* __restrict__ num,
                                              double* __restrict__ P_acc) {
    __shared__ float e_sh[ROWS_PB + 6];
    __shared__ float partials[8][DIM_MEM];
    __shared__ float psum[8];
    const int lane = threadIdx.x & 31;    // half-wave lane: 4 columns each
    const int hw   = threadIdx.x >> 5;    // 8 half-waves per block
    const float4* mem4 = (const float4*)mem;
    const float4 k4 = ((const float4*)keyv)[lane];
    const float d0 = der[0];
    const int r0 = blockIdx.x * ROWS_PB;
    const int rbase = r0 + hw * 8;

    // load this half-wave's 8 rows into registers (one row = 512B contiguous)
    float4 row[8];
    #pragma unroll
    for (int j = 0; j < 8; ++j)
        row[j] = mem4[(size_t)(rbase + j) * 32 + lane];

    // scores for own rows
    #pragma unroll
    for (int j = 0; j < 8; ++j) {
        float dot = row[j].x * k4.x + row[j].y * k4.y + row[j].z * k4.z + row[j].w * k4.w;
        float n2  = row[j].x * row[j].x + row[j].y * row[j].y + row[j].z * row[j].z + row[j].w * row[j].w;
        for (int off = 16; off; off >>= 1) {
            dot += __shfl_xor(dot, off, 32);
            n2  += __shfl_xor(n2,  off, 32);
        }
        if (lane == 0)
            e_sh[3 + hw * 8 + j] = expf(d0 * dot / fmaxf(sqrtf(n2), EPSF));
    }

    // halo scores: hw 0 -> 3 rows left, hw 1 -> 3 rows right (circular)
    if (hw < 2) {
        #pragma unroll
        for (int j = 0; j < 3; ++j) {
            int r = (hw == 0) ? (r0 - 3 + j + N_SLOTS) % N_SLOTS
                              : (r0 + ROWS_PB + j) % N_SLOTS;
            float4 m4 = mem4[(size_t)r * 32 + lane];
            float dot = m4.x * k4.x + m4.y * k4.y + m4.z * k4.z + m4.w * k4.w;
            float n2  = m4.x * m4.x + m4.y * m4.y + m4.z * m4.z + m4.w * m4.w;
            for (int off = 16; off; off >>= 1) {
                dot += __shfl_xor(dot, off, 32);
                n2  += __shfl_xor(n2,  off, 32);
            }
            if (lane == 0)
                e_sh[(hw == 0) ? j : (ROWS_PB + 3 + j)] =
                    expf(d0 * dot / fmaxf(sqrtf(n2), EPSF));
        }
    }
    __syncthreads();

    // stencil + sharpen + accumulate (e_sh reads are half-wave-uniform -> broadcast)
    const float sharp = der[8];
    float sw[7];
    #pragma unroll
    for (int d = 0; d < 7; ++d) sw[d] = der[1 + d];
    float4 acc = make_float4(0.f, 0.f, 0.f, 0.f);
    float wsum = 0.f;
    #pragma unroll
    for (int j = 0; j < 8; ++j) {
        const int i = hw * 8 + j;        // e_sh[i+d], d=0..6 covers i-3..i+3 (offset +3)
        float t = 0.f;
        #pragma unroll
        for (int d = 0; d < 7; ++d) t = fmaf(sw[d], e_sh[i + d], t);
        float w = powf(t, sharp);
        wsum += w;
        acc.x = fmaf(w, row[j].x, acc.x);
        acc.y = fmaf(w, row[j].y, acc.y);
        acc.z = fmaf(w, row[j].z, acc.z);
        acc.w = fmaf(w, row[j].w, acc.w);
    }
    ((float4*)partials[hw])[lane] = acc;
    if (lane == 0) psum[hw] = wsum;
    __syncthreads();

    if (threadIdx.x < DIM_MEM) {
        float s = 0.f;
        #pragma unroll
        for (int h = 0; h < 8; ++h) s += partials[h][threadIdx.x];
        atomicAdd(&num[threadIdx.x], s);
    }
    if (threadIdx.x == 0) {
        float s = 0.f;
        #pragma unroll
        for (int h = 1; h < 8; ++h) s += psum[h];
        atomicAdd(P_acc, (double)(s + psum[0]));
    }
}

// ---- Stage 4: out = num / P ----
__global__ void k_final(const float* __restrict__ num,
                        const double* __restrict__ P_acc,
                        float* __restrict__ out) {
    out[threadIdx.x] = num[threadIdx.x] / (float)(*P_acc);
}

extern "C" void kernel_launch(void* const* d_in, const int* in_sizes, int n_in,
                              void* d_out, int out_size, void* d_ws, size_t ws_size,
                              hipStream_t stream) {
    const float* x   = (const float*)d_in[0];   // input_from_controller (1024)
    // d_in[1] = previous_weighting: unused (gate == 1.0 exactly)
    const float* mem = (const float*)d_in[2];   // memory (N_SLOTS*128)
    const float* W   = (const float*)d_in[3];   // W_wf (1024*138)
    const float* b   = (const float*)d_in[4];   // b_wf (138)
    float* out = (float*)d_out;

    char* ws = (char*)d_ws;
    float*  factors = (float*)ws;
    float*  derived = (float*)(ws + 1024);
    double* P_acc   = (double*)(ws + 2048);
    float*  num     = (float*)(ws + 2176);

    hipMemsetAsync(ws, 0, 4096, stream);   // factors + derived + P + num

    k_factors<<<DIM_IN / 32, 256, 0, stream>>>(x, W, b, factors);
    k_derived<<<1, 64, 0, stream>>>(factors, derived);
    k_main<<<N_SLOTS / ROWS_PB, 256, 0, stream>>>(mem, factors, derived, num, P_acc);
    k_final<<<1, DIM_MEM, 0, stream>>>(num, P_acc, out);
}

// Round 3
// 381.081 us; speedup vs baseline: 1.3259x; 1.3259x over previous
//
#include <hip/hip_runtime.h>
#include <math.h>

#define N_SLOTS 524288
#define DIM_MEM 128
#define DIM_IN 1024
#define NFACT 138
#define EPSF 1e-8f
#define CPB 4               // chunks per block
#define ROWS_PC 64          // rows per chunk
#define NPAIR 70            // 64 own rows + 3 halo each side
#define PAD 33              // LDS stride: (tid+l)%32 -> 2-way conflicts only (free)

// ws layout (bytes), first 4096 zeroed each call:
//   0    : float factors[138]
//   1024 : float derived[16]  d0=key_s/key_norm, d1..d7=shift_w, d8=sharpening
//   2048 : double P_acc
//   2176 : float num[128]

// ---- Stage 1: factors = x @ W + b  (1024 x 138) ----
__global__ __launch_bounds__(256) void k_factors(const float* __restrict__ x,
                                                 const float* __restrict__ W,
                                                 const float* __restrict__ b,
                                                 float* __restrict__ factors) {
    int j = threadIdx.x;
    int i0 = blockIdx.x * 32;
    if (j < NFACT) {
        float acc = 0.f;
        #pragma unroll 8
        for (int i = i0; i < i0 + 32; ++i)
            acc = fmaf(x[i], W[(size_t)i * NFACT + j], acc);
        if (blockIdx.x == 0) acc += b[j];
        atomicAdd(&factors[j], acc);
    }
}

// ---- Stage 2: derived scalars ----
// gate = softmax over ONE element == 1.0 exactly -> previous_weighting dead.
// Content-softmax denominator cancels in (t/S)^sh / sum(...), never computed.
__global__ void k_derived(const float* __restrict__ f, float* __restrict__ d) {
    int l = threadIdx.x;            // 64 threads
    float v = f[l] * f[l] + f[l + 64] * f[l + 64];
    for (int off = 32; off; off >>= 1) v += __shfl_xor(v, off, 64);
    if (l == 0) {
        float key_norm = fmaxf(sqrtf(v), EPSF);
        d[0] = f[128] / key_norm;
        float m = f[130];
        for (int j = 1; j < 7; ++j) m = fmaxf(m, f[130 + j]);
        float e[7], s = 0.f;
        for (int j = 0; j < 7; ++j) { e[j] = expf(f[130 + j] - m); s += e[j]; }
        for (int j = 0; j < 7; ++j) d[1 + j] = e[j] / s;
        d[8] = fmaxf(f[137], 0.f) + 1.f;
    }
}

// ---- Stage 3: fused single pass, LDS-transpose score reduction ----
__global__ __launch_bounds__(256) void k_main(const float* __restrict__ mem,
                                              const float* __restrict__ keyv,
                                              const float* __restrict__ der,
                                              float* __restrict__ num,
                                              double* __restrict__ P_acc) {
    __shared__ float part[2 * NPAIR * PAD];  // [(pair*2+kind)*PAD + lane]
    __shared__ float sums[2 * NPAIR];
    __shared__ float e_sh[NPAIR];            // e_sh[p]: p=0..2 left halo, 3..66 own, 67..69 right halo
    __shared__ float w_sh[ROWS_PC];
    __shared__ float colpart[8][DIM_MEM];
    __shared__ float psum[8];

    const int tid  = threadIdx.x;
    const int lane = tid & 31;               // 4 columns each
    const int hw   = tid >> 5;               // 8 half-waves
    const float4* mem4 = (const float4*)mem;
    const float4 k4 = ((const float4*)keyv)[lane];
    const float d0 = der[0];
    const float sharp = der[8];
    float sw[7];
    #pragma unroll
    for (int d = 0; d < 7; ++d) sw[d] = der[1 + d];

    float4 acc = make_float4(0.f, 0.f, 0.f, 0.f);
    float wsum = 0.f;

    for (int c = 0; c < CPB; ++c) {
        const int r0 = blockIdx.x * (CPB * ROWS_PC) + c * ROWS_PC;
        const int rbase = r0 + hw * 8;

        // Phase A: load own 8 rows (kept in registers), write dot/n2 partials
        float4 row[8];
        #pragma unroll
        for (int j = 0; j < 8; ++j)
            row[j] = mem4[(size_t)(rbase + j) * 32 + lane];
        #pragma unroll
        for (int j = 0; j < 8; ++j) {
            float dp = row[j].x * k4.x + row[j].y * k4.y + row[j].z * k4.z + row[j].w * k4.w;
            float np = row[j].x * row[j].x + row[j].y * row[j].y + row[j].z * row[j].z + row[j].w * row[j].w;
            int p = 3 + hw * 8 + j;
            part[(p * 2 + 0) * PAD + lane] = dp;
            part[(p * 2 + 1) * PAD + lane] = np;
        }
        // halo rows (3 left, 3 right, circular) — one per half-wave 0..5
        if (hw < 6) {
            int hr = (hw < 3) ? (r0 - 3 + hw) : (r0 + ROWS_PC + (hw - 3));
            hr &= (N_SLOTS - 1);
            int p = (hw < 3) ? hw : (64 + hw);          // 0..2 and 67..69
            float4 m4 = mem4[(size_t)hr * 32 + lane];
            part[(p * 2 + 0) * PAD + lane] =
                m4.x * k4.x + m4.y * k4.y + m4.z * k4.z + m4.w * k4.w;
            part[(p * 2 + 1) * PAD + lane] =
                m4.x * m4.x + m4.y * m4.y + m4.z * m4.z + m4.w * m4.w;
        }
        __syncthreads();

        // Phase B1: 140 independent 32-way sums (no dependent chains)
        if (tid < 2 * NPAIR) {
            float s = 0.f;
            #pragma unroll
            for (int l = 0; l < 32; ++l) s += part[tid * PAD + l];
            sums[tid] = s;
        }
        __syncthreads();

        // Phase B2: scores -> e
        if (tid < NPAIR) {
            float dot = sums[tid * 2], n2 = sums[tid * 2 + 1];
            e_sh[tid] = __expf(d0 * dot / fmaxf(sqrtf(n2), EPSF));
        }
        __syncthreads();

        // Phase C: 7-tap stencil + sharpening, one thread per row
        if (tid < ROWS_PC) {
            float t = 0.f;
            #pragma unroll
            for (int d = 0; d < 7; ++d) t = fmaf(sw[d], e_sh[tid + d], t);
            w_sh[tid] = __expf(sharp * __logf(t));      // t > 0 always
        }
        __syncthreads();

        // Phase D: accumulate w * row into per-thread column partials
        #pragma unroll
        for (int j = 0; j < 8; ++j) {
            float w = w_sh[hw * 8 + j];                 // half-wave-uniform broadcast
            acc.x = fmaf(w, row[j].x, acc.x);
            acc.y = fmaf(w, row[j].y, acc.y);
            acc.z = fmaf(w, row[j].z, acc.z);
            acc.w = fmaf(w, row[j].w, acc.w);
            wsum += w;
        }
        __syncthreads();   // part[] reused next chunk
    }

    // Block epilogue: reduce 8 half-wave partials, one atomic per column
    ((float4*)colpart[hw])[lane] = acc;
    if (lane == 0) psum[hw] = wsum;
    __syncthreads();
    if (tid < DIM_MEM) {
        float s = 0.f;
        #pragma unroll
        for (int h = 0; h < 8; ++h) s += colpart[h][tid];
        atomicAdd(&num[tid], s);
    }
    if (tid == 0) {
        float s = 0.f;
        #pragma unroll
        for (int h = 0; h < 8; ++h) s += psum[h];
        atomicAdd(P_acc, (double)s);
    }
}

// ---- Stage 4: out = num / P ----
__global__ void k_final(const float* __restrict__ num,
                        const double* __restrict__ P_acc,
                        float* __restrict__ out) {
    out[threadIdx.x] = num[threadIdx.x] / (float)(*P_acc);
}

extern "C" void kernel_launch(void* const* d_in, const int* in_sizes, int n_in,
                              void* d_out, int out_size, void* d_ws, size_t ws_size,
                              hipStream_t stream) {
    const float* x   = (const float*)d_in[0];   // input_from_controller (1024)
    // d_in[1] = previous_weighting: unused (gate == 1.0 exactly)
    const float* mem = (const float*)d_in[2];   // memory (N_SLOTS*128)
    const float* W   = (const float*)d_in[3];   // W_wf (1024*138)
    const float* b   = (const float*)d_in[4];   // b_wf (138)
    float* out = (float*)d_out;

    char* ws = (char*)d_ws;
    float*  factors = (float*)ws;
    float*  derived = (float*)(ws + 1024);
    double* P_acc   = (double*)(ws + 2048);
    float*  num     = (float*)(ws + 2176);

    hipMemsetAsync(ws, 0, 4096, stream);

    k_factors<<<DIM_IN / 32, 256, 0, stream>>>(x, W, b, factors);
    k_derived<<<1, 64, 0, stream>>>(factors, derived);
    k_main<<<N_SLOTS / (CPB * ROWS_PC), 256, 0, stream>>>(mem, factors, derived, num, P_acc);
    k_final<<<1, DIM_MEM, 0, stream>>>(num, P_acc, out);
}